// Round 5
// baseline (197.705 us; speedup 1.0000x reference)
//
#include <hip/hip_runtime.h>
#include <stdint.h>

// Dyna_Dec: out[b,d,l] = sum_c x[b,c,l] * w[l,c,d] + bias[l,d]
// B=128, C=32, L=4096.
//
// Evidence trail:
//  R3: inputs-as-bf16 -> NaN  => inputs are fp32.
//  R4: fp32 math + bf16-packed store -> finite absmax 4.72 (~= output scale)
//      => harness reads output as fp32 => OUTPUT IS FP32 (matches contract:
//      reference returns float32 -> d_out is float*).
// Roofline: 144.5 MiB HBM traffic -> ~24 us floor @6.3 TB/s; FMA ~7 us.
// Memory-bound; VALU formulation.
//
// Structure: block = 256 thr = 64 l-lanes x 4 b-quadrants, acc[4][32]
// fp32/thread. Grid 64 x 8. x loads / out stores coalesced along l.
// Runtime input-dtype probe kept (wave0 ballot on low-16-bits-as-bf16
// saneness; fp32 inputs ~8% sane, bf16 inputs ~100%) as insurance.

namespace {

constexpr int kB = 128;
constexpr int kC = 32;
constexpr int kL = 4096;
constexpr int kNB = 4;  // batches accumulated per thread

__device__ __forceinline__ float bf_lo(uint32_t u) {
    union { uint32_t u; float f; } v; v.u = u << 16; return v.f;
}
__device__ __forceinline__ float bf_hi(uint32_t u) {
    union { uint32_t u; float f; } v; v.u = u & 0xffff0000u; return v.f;
}

__global__ __launch_bounds__(256, 2)
void dyna_dec(const void* __restrict__ xv,
              const void* __restrict__ wv,
              const void* __restrict__ bv,
              float* __restrict__ out) {
    // ---- input dtype probe: packed bf16 or fp32? ----
    __shared__ int s_is_bf16;
    if (threadIdx.x < 64) {
        const uint32_t word = ((const uint32_t*)xv)[threadIdx.x];
        const float a = fabsf(bf_lo(word & 0xffffu));
        const bool sane = (a == 0.0f) || (a >= 6.103515625e-05f && a <= 32.0f);
        unsigned long long m = __ballot(sane);
        if (threadIdx.x == 0) s_is_bf16 = (__popcll(m) >= 32) ? 1 : 0;
    }
    __syncthreads();

    const int lt = threadIdx.x & 63;           // l within block's 64-l chunk
    const int bq = threadIdx.x >> 6;           // 0..3
    const int l  = blockIdx.x * 64 + lt;       // gridDim.x = L/64 = 64
    const int b0 = blockIdx.y * 16 + bq * kNB; // gridDim.y = B/16 = 8

    float acc[kNB][kC];
#pragma unroll
    for (int i = 0; i < kNB; ++i)
#pragma unroll
        for (int d = 0; d < kC; ++d) acc[i][d] = 0.0f;

    if (!s_is_bf16) {
        // ================= fp32-input path (hot) =================
        const float* x    = (const float*)xv;
        const float* w    = (const float*)wv;
        const float* bias = (const float*)bv;
        const float* wrow = w + (size_t)l * (kC * kC);
        const float* xp   = x + (size_t)b0 * (kC * kL) + l;

#pragma unroll 4
        for (int c = 0; c < kC; ++c) {
            float xr[kNB];
#pragma unroll
            for (int i = 0; i < kNB; ++i)
                xr[i] = xp[(size_t)i * (kC * kL) + (size_t)c * kL];  // coalesced over l
            const float4* wr4 = reinterpret_cast<const float4*>(wrow + c * kC);
#pragma unroll
            for (int q = 0; q < 8; ++q) {
                const float4 wq = wr4[q];
                const float ws[4] = {wq.x, wq.y, wq.z, wq.w};
#pragma unroll
                for (int j = 0; j < 4; ++j) {
                    const int d = q * 4 + j;
#pragma unroll
                    for (int i = 0; i < kNB; ++i)
                        acc[i][d] += xr[i] * ws[j];
                }
            }
        }

        float bvv[kC];
        const float4* br4 = reinterpret_cast<const float4*>(bias + (size_t)l * kC);
#pragma unroll
        for (int q = 0; q < 8; ++q) {
            const float4 bq4 = br4[q];
            bvv[q * 4 + 0] = bq4.x; bvv[q * 4 + 1] = bq4.y;
            bvv[q * 4 + 2] = bq4.z; bvv[q * 4 + 3] = bq4.w;
        }
#pragma unroll
        for (int i = 0; i < kNB; ++i) {
            float* op = out + (size_t)(b0 + i) * (kC * kL) + l;
#pragma unroll
            for (int d = 0; d < kC; ++d)
                op[(size_t)d * kL] = acc[i][d] + bvv[d];  // fp32 store, coalesced over l
        }
    } else {
        // ================= bf16-input path (fallback; fp32 out) =================
        const uint16_t* x    = (const uint16_t*)xv;
        const uint16_t* w    = (const uint16_t*)wv;
        const uint16_t* bias = (const uint16_t*)bv;
        const uint16_t* wrow = w + (size_t)l * (kC * kC);
        const uint16_t* xp   = x + (size_t)b0 * (kC * kL) + l;

#pragma unroll 4
        for (int c = 0; c < kC; ++c) {
            float xr[kNB];
#pragma unroll
            for (int i = 0; i < kNB; ++i)
                xr[i] = bf_lo((uint32_t)xp[(size_t)i * (kC * kL) + (size_t)c * kL]);
            const uint4* wr4 = reinterpret_cast<const uint4*>(wrow + c * kC);
#pragma unroll
            for (int q = 0; q < 4; ++q) {
                const uint4 pk = wr4[q];
                const uint32_t ws[4] = {pk.x, pk.y, pk.z, pk.w};
#pragma unroll
                for (int j = 0; j < 4; ++j) {
                    const float w0 = bf_lo(ws[j]);
                    const float w1 = bf_hi(ws[j]);
                    const int d = q * 8 + j * 2;
#pragma unroll
                    for (int i = 0; i < kNB; ++i) {
                        acc[i][d]     += xr[i] * w0;
                        acc[i][d + 1] += xr[i] * w1;
                    }
                }
            }
        }

        float bvv[kC];
        const uint4* br4 = reinterpret_cast<const uint4*>(bias + (size_t)l * kC);
#pragma unroll
        for (int q = 0; q < 4; ++q) {
            const uint4 pk = br4[q];
            const uint32_t bs[4] = {pk.x, pk.y, pk.z, pk.w};
#pragma unroll
            for (int j = 0; j < 4; ++j) {
                bvv[q * 8 + j * 2]     = bf_lo(bs[j]);
                bvv[q * 8 + j * 2 + 1] = bf_hi(bs[j]);
            }
        }
#pragma unroll
        for (int i = 0; i < kNB; ++i) {
            float* op = out + (size_t)(b0 + i) * (kC * kL) + l;
#pragma unroll
            for (int d = 0; d < kC; ++d)
                op[(size_t)d * kL] = acc[i][d] + bvv[d];
        }
    }
}

}  // namespace

extern "C" void kernel_launch(void* const* d_in, const int* in_sizes, int n_in,
                              void* d_out, int out_size, void* d_ws, size_t ws_size,
                              hipStream_t stream) {
    // inputs: 0=x (B,C,H,W), 1=px (unused), 2=weight (L*C, C), 3=bias (L*C)
    const void* x    = d_in[0];
    const void* wgt  = d_in[2];
    const void* bias = d_in[3];
    float* out = (float*)d_out;

    dim3 grid(kL / 64, kB / 16);
    dim3 block(256);
    hipLaunchKernelGGL(dyna_dec, grid, block, 0, stream, x, wgt, bias, out);
}

// Round 6
// 180.893 us; speedup vs baseline: 1.0929x; 1.0929x over previous
//
#include <hip/hip_runtime.h>
#include <stdint.h>

// Dyna_Dec: out[b,d,l] = sum_c x[b,c,l] * w[l,c,d] + bias[l,d]
// B=128, C=32, L=4096. Inputs fp32, output fp32 (R5 passed, absmax 0.0).
//
// R5 counters: dur 105us, VALUBusy 8%, hbm 14%, Occupancy 16% -> pure
// latency bound (512 blocks = 2 waves/SIMD; 128-FMA dep chains; 12 scattered
// loads/iter). Traffic is compulsory (FETCH 49MB, WRITE 68MB).
//
// R6: d-split across waves. Block = 256 thr = 64 l-lanes (lt) x 4 d-groups
// (dg). Thread owns acc[8 b][8 d] = 64 VGPRs. Grid 64 x 16 = 1024 blocks =
// 4 blocks/CU = 16 waves/CU (50% occ). Per c-iter per thread: 2x dwordx4 W
// (the 4 dg-waves tile the W row exactly once — no intra-block W redundancy)
// + 8 coalesced x dwords (x4 redundant across dg-waves, L1-served) + 64 FMA.
// blockIdx linearization keeps all 16 b-blocks of one l-chunk on one XCD
// (id%8 == blockIdx.x%8) -> W slice L2-resident.

namespace {

constexpr int kC  = 32;
constexpr int kL  = 4096;
constexpr int kNB = 8;  // batches per thread
constexpr int kND = 8;  // d-channels per thread

__global__ __launch_bounds__(256, 4)
void dyna_dec(const float* __restrict__ x,
              const float* __restrict__ w,
              const float* __restrict__ bias,
              float* __restrict__ out) {
    const int lt = threadIdx.x & 63;   // lane = l within chunk (coalescing dim)
    const int dg = threadIdx.x >> 6;   // wave = d-group 0..3
    const int l  = blockIdx.x * 64 + lt;        // gridDim.x = L/64 = 64
    const int b0 = blockIdx.y * kNB;            // gridDim.y = B/8  = 16
    const int d0 = dg * kND;

    const float* wp = w + (size_t)l * (kC * kC) + d0;  // W[l, c, d0..d0+7]
    const float* xp = x + (size_t)b0 * (kC * kL) + l;  // x[b0, 0, l]

    float acc[kNB][kND];
#pragma unroll
    for (int i = 0; i < kNB; ++i)
#pragma unroll
        for (int j = 0; j < kND; ++j) acc[i][j] = 0.0f;

#pragma unroll 2
    for (int c = 0; c < kC; ++c) {
        // W[l, c, d0..d0+7]: 32 B, 16B-aligned (lane-scattered 4KB stride,
        // L1/L2-resident; the 4 dg-waves consume the full 128B row once)
        const float4 w0 = *reinterpret_cast<const float4*>(wp + c * kC);
        const float4 w1 = *reinterpret_cast<const float4*>(wp + c * kC + 4);
        const float ws[kND] = {w0.x, w0.y, w0.z, w0.w, w1.x, w1.y, w1.z, w1.w};

        // x[b0+i, c, l]: coalesced over lanes, 8 independent loads
        float xr[kNB];
#pragma unroll
        for (int i = 0; i < kNB; ++i)
            xr[i] = xp[(size_t)i * (kC * kL) + (size_t)c * kL];

#pragma unroll
        for (int i = 0; i < kNB; ++i)
#pragma unroll
            for (int j = 0; j < kND; ++j)
                acc[i][j] += xr[i] * ws[j];
    }

    // bias[l, d0..d0+7]
    const float4 b0v = *reinterpret_cast<const float4*>(bias + (size_t)l * kC + d0);
    const float4 b1v = *reinterpret_cast<const float4*>(bias + (size_t)l * kC + d0 + 4);
    const float bv[kND] = {b0v.x, b0v.y, b0v.z, b0v.w, b1v.x, b1v.y, b1v.z, b1v.w};

#pragma unroll
    for (int i = 0; i < kNB; ++i) {
        float* op = out + (size_t)(b0 + i) * (kC * kL) + l;
#pragma unroll
        for (int j = 0; j < kND; ++j)
            op[(size_t)(d0 + j) * kL] = acc[i][j] + bv[j];  // coalesced over l
    }
}

}  // namespace

extern "C" void kernel_launch(void* const* d_in, const int* in_sizes, int n_in,
                              void* d_out, int out_size, void* d_ws, size_t ws_size,
                              hipStream_t stream) {
    // inputs: 0=x (B,C,H,W) fp32, 1=px (unused), 2=weight (L*C, C) fp32,
    //         3=bias (L*C) fp32
    const float* x    = (const float*)d_in[0];
    const float* wgt  = (const float*)d_in[2];
    const float* bias = (const float*)d_in[3];
    float* out = (float*)d_out;

    dim3 grid(kL / 64, 128 / kNB);  // 64 x 16 = 1024 blocks
    dim3 block(256);
    hipLaunchKernelGGL(dyna_dec, grid, block, 0, stream, x, wgt, bias, out);
}